// Round 8
// baseline (198.243 us; speedup 1.0000x reference)
//
#include <hip/hip_runtime.h>

// MFMA fragment types (gfx950): 16x16x32 f16 -> A/B = 8 x _Float16, C/D = 4 x float
typedef _Float16 half8 __attribute__((ext_vector_type(8)));
typedef __fp16 fp16x2 __attribute__((ext_vector_type(2)));   // cvt_pkrtz return type
typedef float floatx4 __attribute__((ext_vector_type(4)));

#define MSGW 64      // message width
#define DEG 8        // fixed in-degree; triplets per edge

// softplus(x) = ln(1 + e^x) = ln2 * log2(1 + exp2(log2e * x))
// 5 VALU ops; valid for x < ~88 (exp2 overflow), net's pre-activations |x| <~ 50.
__device__ __forceinline__ float softplus_f(float x) {
    float t = __builtin_amdgcn_exp2f(1.44269504089f * x);    // e^x
    return 0.69314718056f * __builtin_amdgcn_logf(1.0f + t); // ln(1+e^x)
}

__device__ __forceinline__ half8 cvt8(const float* p) {
    float4 x = *(const float4*)p;
    float4 y = *(const float4*)(p + 4);
    fp16x2 p0 = __builtin_amdgcn_cvt_pkrtz(x.x, x.y);
    fp16x2 p1 = __builtin_amdgcn_cvt_pkrtz(x.z, x.w);
    fp16x2 p2 = __builtin_amdgcn_cvt_pkrtz(y.x, y.y);
    fp16x2 p3 = __builtin_amdgcn_cvt_pkrtz(y.z, y.w);
    half8 h;
    h[0] = (_Float16)p0[0]; h[1] = (_Float16)p0[1];
    h[2] = (_Float16)p1[0]; h[3] = (_Float16)p1[1];
    h[4] = (_Float16)p2[0]; h[5] = (_Float16)p2[1];
    h[6] = (_Float16)p3[0]; h[7] = (_Float16)p3[1];
    return h;
}

// softplus over a half8 (fp16 in, fp16 out via cvt_pkrtz pairs)
__device__ __forceinline__ half8 sp8(half8 z) {
    half8 h;
#pragma unroll
    for (int j = 0; j < 8; j += 2) {
        fp16x2 pk = __builtin_amdgcn_cvt_pkrtz(softplus_f((float)z[j]),
                                               softplus_f((float)z[j + 1]));
        h[j] = (_Float16)pk[0]; h[j + 1] = (_Float16)pk[1];
    }
    return h;
}

// DPP-based cross-lane adds (register-only, no DS pipe).
template<int CTRL>
__device__ __forceinline__ float dpp_addf(float x) {
    int y = __builtin_amdgcn_update_dpp(0, __float_as_int(x), CTRL, 0xF, 0xF, true);
    return x + __int_as_float(y);
}
// full sum over the 16 lanes of a DPP row
__device__ __forceinline__ float red16(float x) {
    x = dpp_addf<0xB1>(x);   // pair sums
    x = dpp_addf<0x4E>(x);   // quad sums
    x = dpp_addf<0x141>(x);  // 8-lane sums
    x = dpp_addf<0x140>(x);  // 16-lane sum (all lanes)
    return x;
}
// sum over each 8-lane half of a DPP row
__device__ __forceinline__ float red8(float x) {
    x = dpp_addf<0xB1>(x);
    x = dpp_addf<0x4E>(x);
    x = dpp_addf<0x141>(x);
    return x;
}

// ---------------------------------------------------------------------------
// Kernel 1 (fused prep + projection):
//   - grid-stride zero of sacc/cnt (float4 stores)
//   - stage W1 -> LDS in MFMA B-fragment lane order directly from global
//   - PQ[e][0:64]   = messages[e] @ W1[0:64, :]          (P, consumed via kj)
//     PQ[e][64:128] = messages[e] @ W1[64:128, :] + b1   (Q, consumed via ji)
// Stored fp16, [E x 128]. One wave = 16 edge rows, 16 MFMAs, one tile/wave.
// ---------------------------------------------------------------------------
__global__ __launch_bounds__(256, 2)
void edge_proj_kernel(const float* __restrict__ messages,
                      const float* __restrict__ W1, const float* __restrict__ b1,
                      _Float16* __restrict__ PQ, int E,
                      float4* __restrict__ zs, int nz4)
{
    __shared__ __align__(16) _Float16 lw1x[16 * 512];     // 16 B-fragments, lane-order
    __shared__ __align__(16) _Float16 lrep[4][16 * 132];  // per-wave C->row repack

    const int tid = threadIdx.x;

    // zero accumulators (grid-strided; 2500 blocks cover 25000 float4)
    {
        float4 z = {0.f, 0.f, 0.f, 0.f};
        for (int i = blockIdx.x * 256 + tid; i < nz4; i += gridDim.x * 256) zs[i] = z;
    }

    // stage W1: row-major [128][64]; rows 0..63 -> P cols, rows 64..127 -> Q cols
    for (int i = tid; i < 128 * 64; i += 256) {
        int r = i >> 6, c = i & 63;
        int k  = (r < 64) ? r : (r - 64);
        int np = (r < 64) ? c : (64 + c);
        int f  = (np >> 4) * 2 + (k >> 5);
        int ln = ((k >> 3) & 3) * 16 + (np & 15);
        lw1x[f * 512 + ln * 8 + (k & 7)] = (_Float16)W1[i];
    }
    __syncthreads();

    const int wave = tid >> 6;
    const int lane = tid & 63;
    const int s = lane & 15;
    const int q = lane >> 4;
    const int e0 = (blockIdx.x * 4 + wave) * 16;
    if (e0 >= E) return;

    float b1v[4];
#pragma unroll
    for (int nt = 0; nt < 4; ++nt) b1v[nt] = b1[nt * 16 + s];

    int er = e0 + s; if (er >= E) er = E - 1;
    const float* mp = messages + (size_t)er * MSGW + q * 8;
    half8 af0 = cvt8(mp);
    half8 af1 = cvt8(mp + 32);

    floatx4 acc[8];
#pragma unroll
    for (int nt = 0; nt < 4; ++nt) { floatx4 z = {0.f, 0.f, 0.f, 0.f}; acc[nt] = z; }
#pragma unroll
    for (int nt = 4; nt < 8; ++nt) {
        float bv = b1v[nt - 4];
        floatx4 iv = {bv, bv, bv, bv};
        acc[nt] = iv;
    }
#pragma unroll
    for (int nt = 0; nt < 8; ++nt) {
        half8 bf0 = *(const half8*)&lw1x[(nt * 2 + 0) * 512 + lane * 8];
        acc[nt] = __builtin_amdgcn_mfma_f32_16x16x32_f16(af0, bf0, acc[nt], 0, 0, 0);
        half8 bf1 = *(const half8*)&lw1x[(nt * 2 + 1) * 512 + lane * 8];
        acc[nt] = __builtin_amdgcn_mfma_f32_16x16x32_f16(af1, bf1, acc[nt], 0, 0, 0);
    }

    // C-layout -> row-major fp16 via wave-private LDS, then coalesced 16B stores.
    _Float16* rep = lrep[wave];
#pragma unroll
    for (int nt = 0; nt < 8; ++nt)
#pragma unroll
        for (int rr = 0; rr < 4; ++rr)
            rep[(q * 4 + rr) * 132 + nt * 16 + s] = (_Float16)acc[nt][rr];
    __asm__ volatile("s_waitcnt lgkmcnt(0)" ::: "memory");

#pragma unroll
    for (int cc = 0; cc < 4; ++cc) {
        int c = cc * 64 + lane;
        int rrow = c >> 4, c16 = c & 15;
        half8 v = *(const half8*)&rep[rrow * 132 + c16 * 8];
        int eg = e0 + rrow;
        if (eg < E)
            *(half8*)&PQ[(size_t)eg * 128 + c16 * 8] = v;
    }
}

// ---------------------------------------------------------------------------
// Kernel 2: main triplet kernel. TWO independent 16-triplet tiles per wave
// per iteration (ILP x2): per-wave dependency bubbles (serial softplus chain,
// 4-deep DPP red16) of one tile are filled by the other tile's instructions.
// Both tiles' compute is branch-free straight-line (atomics deferred to a
// trailing section; rotation last) so the scheduler can interleave freely.
// Zero LDS, no barriers, NO epilogue sync (R4/R5 lesson: fused cross-block
// finalize cost ~245us idle tail; keep finalize a separate 4us dispatch).
// W2 fragments gathered once per lane directly from W2 (16 KB, L2-hot).
// PQ/rk/rj software-pipelined one tile ahead (idx two ahead).
// Structural facts: idx_ji[t]=t>>3, idx_j[t]=idx_kj[t]>>3.
// launch_bounds (256,3): VGPR cap ~168. R4's (256,6) squeezed to 40 VGPR and
// spilled (WRITE_SIZE 10->117MB, 6.5x slower). DO NOT raise the wave hint.
// ---------------------------------------------------------------------------
__global__ __launch_bounds__(256, 3)
void triplet_mlp2_kernel(const _Float16* __restrict__ PQ,
                         const float* __restrict__ r2,
                         const float* __restrict__ W2,
                         const float* __restrict__ b2,
                         const float* __restrict__ W3, const float* __restrict__ b3,
                         const int* __restrict__ idx_kj,
                         float* __restrict__ sacc, float* __restrict__ cnt,
                         int nChunks)
{
    const int tid = threadIdx.x;
    const int wave = tid >> 6;
    const int lane = tid & 63;
    const int s = lane & 15;
    const int q = lane >> 4;

    // hoist weights: W2 fragments (32 VGPR) gathered with permuted addressing.
    // w2f[ks][nt][j] = W2[k = ks*32 + q*8 + j][n = nt*16 + s]
    half8 w2f[2][4];
#pragma unroll
    for (int ks = 0; ks < 2; ++ks)
#pragma unroll
        for (int nt = 0; nt < 4; ++nt) {
            half8 h;
#pragma unroll
            for (int j = 0; j < 8; ++j)
                h[j] = (_Float16)W2[(ks * 32 + q * 8 + j) * 64 + nt * 16 + s];
            w2f[ks][nt] = h;
        }
    float b2v[4], w3v[4];
#pragma unroll
    for (int nt = 0; nt < 4; ++nt) {
        b2v[nt] = b2[nt * 16 + s];
        w3v[nt] = W3[nt * 16 + s];
    }
    const float b3v = b3[0];
    const int aa = q >> 1;                       // dyad row component this lane handles
    const int bb = q & 1;                        // dyad col component
    // bpermute source lane for the m-distribute: lane (s,q) pulls from lane (s>>2)*16 + s
    const int bperm_addr = (((s >> 2) << 4) + s) << 2;

    const int T = nChunks * 128;                 // 128 triplets per chunk (2 tiles/wave)
    const int stride = gridDim.x * 128;

    // ---- pipeline prologue (2 tiles of state) ----
    int t[2], kjv[2], kjn[2], t1c[2];
    half8 p0[2], p1[2], q0[2], q1[2];
    float2 rkv[2];
    float rjv[2];
#pragma unroll
    for (int u = 0; u < 2; ++u) {
        t[u] = blockIdx.x * 128 + wave * 32 + u * 16 + s;    // < T (grid <= nChunks)
        kjv[u] = idx_kj[t[u]];
        int t1 = t[u] + stride; t1c[u] = (t1 < T) ? t1 : 0;
        kjn[u] = idx_kj[t1c[u]];
        const _Float16* pk = PQ + (size_t)kjv[u] * 128 + q * 8;
        const _Float16* pj = PQ + (size_t)(t[u] >> 3) * 128 + 64 + q * 8;
        p0[u] = *(const half8*)pk;
        p1[u] = *(const half8*)(pk + 32);
        q0[u] = *(const half8*)pj;
        q1[u] = *(const half8*)(pj + 32);
        rkv[u] = *(const float2*)(r2 + (size_t)kjv[u] * 2);
        rjv[u] = r2[(size_t)(t[u] >> 3) * 2 + aa];
    }

    for (int chunk = blockIdx.x; chunk < nChunks; chunk += gridDim.x) {
        int kj2[2], t2c[2];
        half8 np0[2], np1[2], nq0[2], nq1[2];
        float2 nrk[2];
        float nrj[2];
        float cval[2];
        int jnv[2];

        // ---- phase 1: prefetch + compute, both tiles, branch-free ----
#pragma unroll
        for (int u = 0; u < 2; ++u) {
            // idx two tiles ahead; PQ/rk/rj one tile ahead
            int t2 = t[u] + 2 * stride; t2c[u] = (t2 < T) ? t2 : 0;
            kj2[u] = idx_kj[t2c[u]];
            const _Float16* pkn = PQ + (size_t)kjn[u] * 128 + q * 8;
            const _Float16* pjn = PQ + (size_t)(t1c[u] >> 3) * 128 + 64 + q * 8;
            np0[u] = *(const half8*)pkn;
            np1[u] = *(const half8*)(pkn + 32);
            nq0[u] = *(const half8*)pjn;
            nq1[u] = *(const half8*)(pjn + 32);
            nrk[u] = *(const float2*)(r2 + (size_t)kjn[u] * 2);
            nrj[u] = r2[(size_t)(t1c[u] >> 3) * 2 + aa];

            jnv[u] = kjv[u] >> 3;                // idx_j structural

            // layer 1 = fp16 add of prefetched PQ fragments + softplus (A-frag layout)
            half8 a20 = sp8(p0[u] + q0[u]);
            half8 a21 = sp8(p1[u] + q1[u]);

            // layer 2: [16 x 64] @ [64 x 64], B from registers
            floatx4 acc2[4];
#pragma unroll
            for (int nt = 0; nt < 4; ++nt) {
                float bv = b2v[nt];
                floatx4 iv = {bv, bv, bv, bv};
                acc2[nt] = iv;
            }
#pragma unroll
            for (int nt = 0; nt < 4; ++nt) {
                acc2[nt] = __builtin_amdgcn_mfma_f32_16x16x32_f16(a20, w2f[0][nt], acc2[nt], 0, 0, 0);
                acc2[nt] = __builtin_amdgcn_mfma_f32_16x16x32_f16(a21, w2f[1][nt], acc2[nt], 0, 0, 0);
            }

            // layer 3: m = softplus(h2) . W3 ; reduce over 64 cols = 4 regs x 16 lanes
            float part[4];
#pragma unroll
            for (int rr = 0; rr < 4; ++rr) {
                float p = 0.0f;
#pragma unroll
                for (int nt = 0; nt < 4; ++nt)
                    p += softplus_f(acc2[nt][rr]) * w3v[nt];
                part[rr] = red16(p);             // all 16 row-lanes: msum[q*4+rr]
            }

            // distribute m to row-owner lanes: local reg-select then one bpermute
            const int rsel = s & 3;
            float mm = part[0];
            mm = (rsel == 1) ? part[1] : mm;
            mm = (rsel == 2) ? part[2] : mm;
            mm = (rsel == 3) ? part[3] : mm;     // lane (s,q) holds msum[q*4 + (s&3)]
            mm = __int_as_float(__builtin_amdgcn_ds_bpermute(bperm_addr, __float_as_int(mm)));
            mm += b3v;                           // lane (s,q) holds m for row s

            // per-edge pooled vector v[b] = sum_k m_k * rk_k[b]; quads carry b = q&1
            float c = mm * ((q & 1) ? rkv[u].y : rkv[u].x);
            cval[u] = red8(c);                   // lanes 0..7: edge A, 8..15: edge B
        }

        // ---- phase 2: atomics for both tiles (exec-masked, end of body) ----
#pragma unroll
        for (int u = 0; u < 2; ++u) {
            if ((s & 7) == 0) {
                atomicAdd(&sacc[(size_t)jnv[u] * 4 + aa * 2 + bb], rjv[u] * cval[u]);
                if (q == 0) atomicAdd(&cnt[jnv[u]], 8.0f);   // 8 triplets pooled per edge
            }
        }

        // ---- phase 3: rotate pipeline state ----
#pragma unroll
        for (int u = 0; u < 2; ++u) {
            t[u] += stride;
            kjv[u] = kjn[u]; kjn[u] = kj2[u];
            t1c[u] = t2c[u];
            p0[u] = np0[u]; p1[u] = np1[u]; q0[u] = nq0[u]; q1[u] = nq1[u];
            rkv[u] = nrk[u]; rjv[u] = nrj[u];
        }
    }
}

// ---------------------------------------------------------------------------
// Fallback: verified single-pass kernel (used if ws/shape can't take fast path)
// ---------------------------------------------------------------------------
__global__ __launch_bounds__(256, 3)
void triplet_mlp_fb_kernel(const float* __restrict__ messages,
                           const float* __restrict__ r2,
                           const float* __restrict__ W1, const float* __restrict__ b1,
                           const float* __restrict__ W2, const float* __restrict__ b2,
                           const float* __restrict__ W3, const float* __restrict__ b3,
                           const int* __restrict__ idx_kj,
                           float* __restrict__ sacc, float* __restrict__ cnt,
                           int nChunks)
{
    __shared__ _Float16 lw1x[16 * 512];
    __shared__ _Float16 lw2x[8 * 512];
    __shared__ float lb1[64], lb2[64], lw3[64];
    __shared__ _Float16 lh[4][16 * 72];

    const int tid = threadIdx.x;
    for (int i = tid; i < 128 * 64; i += 256) {
        int k = i >> 6, n = i & 63;
        int ks = k >> 5, q = (k >> 3) & 3, j = k & 7;
        int nt = n >> 4, s = n & 15;
        lw1x[(nt * 4 + ks) * 512 + (q * 16 + s) * 8 + j] = (_Float16)W1[i];
    }
    for (int i = tid; i < 64 * 64; i += 256) {
        int k = i >> 6, n = i & 63;
        int ks = k >> 5, q = (k >> 3) & 3, j = k & 7;
        int nt = n >> 4, s = n & 15;
        lw2x[(nt * 2 + ks) * 512 + (q * 16 + s) * 8 + j] = (_Float16)W2[i];
    }
    if (tid < 64) { lb1[tid] = b1[tid]; lb2[tid] = b2[tid]; lw3[tid] = W3[tid]; }
    __syncthreads();

    const int wave = tid >> 6;
    const int lane = tid & 63;
    const int s = lane & 15;
    const int q = lane >> 4;
    const float b3v = b3[0];
    const int T = nChunks * 64;
    const int stride = gridDim.x * 64;

    _Float16* myh = lh[wave];

    int t = blockIdx.x * 64 + wave * 16 + s;
    int kj = (t < T) ? idx_kj[t] : 0;

    for (int chunk = blockIdx.x; chunk < nChunks; chunk += gridDim.x) {
        const int t_next = t + stride;
        const int kj_next = idx_kj[(t_next < T) ? t_next : 0];

        const int ji = t >> 3;
        const int jn = kj >> 3;

        const float* mk = messages + (size_t)kj * MSGW + q * 8;
        const float* mj = messages + (size_t)ji * MSGW + q * 8;
        half8 afr[4];
        afr[0] = cvt8(mk);
        afr[1] = cvt8(mk + 32);
        afr[2] = cvt8(mj);
        afr[3] = cvt8(mj + 32);

        const float rk0 = r2[(size_t)kj * 2];
        const float rk1 = r2[(size_t)kj * 2 + 1];

        floatx4 acc[4];
#pragma unroll
        for (int nt = 0; nt < 4; ++nt) {
            float bv = lb1[nt * 16 + s];
            floatx4 iv = {bv, bv, bv, bv};
            acc[nt] = iv;
        }
#pragma unroll
        for (int ks = 0; ks < 4; ++ks)
#pragma unroll
            for (int nt = 0; nt < 4; ++nt) {
                half8 bf = *(const half8*)&lw1x[(nt * 4 + ks) * 512 + lane * 8];
                acc[nt] = __builtin_amdgcn_mfma_f32_16x16x32_f16(afr[ks], bf, acc[nt], 0, 0, 0);
            }

#pragma unroll
        for (int nt = 0; nt < 4; ++nt)
#pragma unroll
            for (int rr = 0; rr < 4; ++rr)
                myh[(q * 4 + rr) * 72 + nt * 16 + s] = (_Float16)softplus_f(acc[nt][rr]);
        __asm__ volatile("s_waitcnt lgkmcnt(0)" ::: "memory");

        half8 a2[2];
        a2[0] = *(const half8*)&myh[s * 72 + q * 8];
        a2[1] = *(const half8*)&myh[s * 72 + 32 + q * 8];
        __asm__ volatile("" ::: "memory");

        floatx4 acc2[4];
#pragma unroll
        for (int nt = 0; nt < 4; ++nt) {
            float bv = lb2[nt * 16 + s];
            floatx4 iv = {bv, bv, bv, bv};
            acc2[nt] = iv;
        }
#pragma unroll
        for (int ks = 0; ks < 2; ++ks)
#pragma unroll
            for (int nt = 0; nt < 4; ++nt) {
                half8 bf = *(const half8*)&lw2x[(nt * 2 + ks) * 512 + lane * 8];
                acc2[nt] = __builtin_amdgcn_mfma_f32_16x16x32_f16(a2[ks], bf, acc2[nt], 0, 0, 0);
            }

        float part[4];
#pragma unroll
        for (int rr = 0; rr < 4; ++rr) {
            float p = 0.0f;
#pragma unroll
            for (int nt = 0; nt < 4; ++nt)
                p += softplus_f(acc2[nt][rr]) * lw3[nt * 16 + s];
            part[rr] = p;
        }
#pragma unroll
        for (int mask = 1; mask < 16; mask <<= 1)
#pragma unroll
            for (int rr = 0; rr < 4; ++rr)
                part[rr] += __shfl_xor(part[rr], mask, 16);

        const int srcl = (s >> 2) << 4;
        float mr[4];
#pragma unroll
        for (int rr = 0; rr < 4; ++rr)
            mr[rr] = __shfl(part[rr], srcl, 64);
        const int rsel = s & 3;
        float m_mine = mr[0];
        m_mine = (rsel == 1) ? mr[1] : m_mine;
        m_mine = (rsel == 2) ? mr[2] : m_mine;
        m_mine = (rsel == 3) ? mr[3] : m_mine;
        m_mine += b3v;

        float c = m_mine * ((q & 1) ? rk1 : rk0);
        c += __shfl_xor(c, 1, 16);
        c += __shfl_xor(c, 2, 16);
        c += __shfl_xor(c, 4, 16);

        if ((s & 7) == 0) {
            const int aa = q >> 1, bb = q & 1;
            const float rj = r2[(size_t)ji * 2 + aa];
            atomicAdd(&sacc[(size_t)jn * 4 + aa * 2 + bb], rj * c);
            if (q == 0) atomicAdd(&cnt[jn], 8.0f);
        }

        t = t_next;
        kj = kj_next;
    }
}

__global__ void finalize_kernel(const float* __restrict__ sacc, const float* __restrict__ cnt,
                                float* __restrict__ out, int n4) {
    int i = blockIdx.x * 256 + threadIdx.x;
    if (i < n4) {
        float c = cnt[i >> 2];
        out[i] = sacc[i] / fmaxf(c, 1.0f);
    }
}

extern "C" void kernel_launch(void* const* d_in, const int* in_sizes, int n_in,
                              void* d_out, int out_size, void* d_ws, size_t ws_size,
                              hipStream_t stream) {
    const float* messages = (const float*)d_in[0];
    const float* r2       = (const float*)d_in[1];
    const float* W1       = (const float*)d_in[2];
    const float* b1       = (const float*)d_in[3];
    const float* W2       = (const float*)d_in[4];
    const float* b2       = (const float*)d_in[5];
    const float* W3       = (const float*)d_in[6];
    const float* b3       = (const float*)d_in[7];
    const int* idx_kj     = (const int*)d_in[8];

    const int T = in_sizes[8];          // 1,280,000 triplets
    const int E = T / DEG;              // 160,000 edges
    const int N = out_size / 4;         // 20,000 nodes
    float* sacc = (float*)d_ws;         // [N*4] pooled sums
    float* cntp = sacc + (size_t)N * 4; // [N] counts

    const int n4 = N * 4;

    // zeroed span: N*5 floats (sacc+cnt), in float4 units (N*5 divisible by 4)
    const int nz4 = (N * 5) / 4;
    const size_t zBytes = (size_t)nz4 * 16;
    const size_t pqOff  = (zBytes + 255) & ~(size_t)255;
    const size_t needWs = pqOff + (size_t)E * 128 * sizeof(_Float16);

    if (ws_size >= needWs && (T % 128) == 0) {
        _Float16* PQ = (_Float16*)((char*)d_ws + pqOff);

        const int tiles = (E + 15) / 16;            // 16-edge wave tiles
        const int epgrid = (tiles + 3) / 4;         // one tile per wave, 4 waves/block
        edge_proj_kernel<<<epgrid, 256, 0, stream>>>(messages, W1, b1, PQ, E,
                                                     (float4*)d_ws, nz4);

        const int nChunks = T / 128;                // 128 triplets/chunk (2 tiles/wave)
        int grid = nChunks < 2048 ? nChunks : 2048;
        triplet_mlp2_kernel<<<grid, 256, 0, stream>>>(PQ, r2, W2, b2, W3, b3,
                                                      idx_kj, sacc, cntp, nChunks);
    } else {
        const int nChunks = T / 64;
        int grid = nChunks < 2048 ? nChunks : 2048;
        (void)hipMemsetAsync(d_ws, 0, (size_t)N * 5 * sizeof(float), stream);
        triplet_mlp_fb_kernel<<<grid, 256, 0, stream>>>(messages, r2, W1, b1, W2, b2, W3, b3,
                                                        idx_kj, sacc, cntp, nChunks);
    }

    finalize_kernel<<<(n4 + 255) / 256, 256, 0, stream>>>(sacc, cntp, (float*)d_out, n4);
}

// Round 9
// 196.438 us; speedup vs baseline: 1.0092x; 1.0092x over previous
//
#include <hip/hip_runtime.h>

// MFMA fragment types (gfx950): 16x16x32 f16 -> A/B = 8 x _Float16, C/D = 4 x float
typedef _Float16 half8 __attribute__((ext_vector_type(8)));
typedef __fp16 fp16x2 __attribute__((ext_vector_type(2)));   // cvt_pkrtz return type
typedef float floatx4 __attribute__((ext_vector_type(4)));

#define MSGW 64      // message width
#define DEG 8        // fixed in-degree; triplets per edge

// softplus(x) = ln(1 + e^x) = ln2 * log2(1 + exp2(log2e * x))
// 5 VALU ops; valid for x < ~88 (exp2 overflow), net's pre-activations |x| <~ 50.
__device__ __forceinline__ float softplus_f(float x) {
    float t = __builtin_amdgcn_exp2f(1.44269504089f * x);    // e^x
    return 0.69314718056f * __builtin_amdgcn_logf(1.0f + t); // ln(1+e^x)
}

__device__ __forceinline__ half8 cvt8(const float* p) {
    float4 x = *(const float4*)p;
    float4 y = *(const float4*)(p + 4);
    fp16x2 p0 = __builtin_amdgcn_cvt_pkrtz(x.x, x.y);
    fp16x2 p1 = __builtin_amdgcn_cvt_pkrtz(x.z, x.w);
    fp16x2 p2 = __builtin_amdgcn_cvt_pkrtz(y.x, y.y);
    fp16x2 p3 = __builtin_amdgcn_cvt_pkrtz(y.z, y.w);
    half8 h;
    h[0] = (_Float16)p0[0]; h[1] = (_Float16)p0[1];
    h[2] = (_Float16)p1[0]; h[3] = (_Float16)p1[1];
    h[4] = (_Float16)p2[0]; h[5] = (_Float16)p2[1];
    h[6] = (_Float16)p3[0]; h[7] = (_Float16)p3[1];
    return h;
}

// softplus over a half8 (fp16 in, fp16 out via cvt_pkrtz pairs)
__device__ __forceinline__ half8 sp8(half8 z) {
    half8 h;
#pragma unroll
    for (int j = 0; j < 8; j += 2) {
        fp16x2 pk = __builtin_amdgcn_cvt_pkrtz(softplus_f((float)z[j]),
                                               softplus_f((float)z[j + 1]));
        h[j] = (_Float16)pk[0]; h[j + 1] = (_Float16)pk[1];
    }
    return h;
}

// DPP-based cross-lane adds (register-only, no DS pipe).
template<int CTRL>
__device__ __forceinline__ float dpp_addf(float x) {
    int y = __builtin_amdgcn_update_dpp(0, __float_as_int(x), CTRL, 0xF, 0xF, true);
    return x + __int_as_float(y);
}
// full sum over the 16 lanes of a DPP row
__device__ __forceinline__ float red16(float x) {
    x = dpp_addf<0xB1>(x);   // pair sums
    x = dpp_addf<0x4E>(x);   // quad sums
    x = dpp_addf<0x141>(x);  // 8-lane sums
    x = dpp_addf<0x140>(x);  // 16-lane sum (all lanes)
    return x;
}
// sum over each 8-lane half of a DPP row
__device__ __forceinline__ float red8(float x) {
    x = dpp_addf<0xB1>(x);
    x = dpp_addf<0x4E>(x);
    x = dpp_addf<0x141>(x);
    return x;
}

// ---------------------------------------------------------------------------
// Kernel 1 (fused prep + projection):
//   - grid-stride zero of sacc/cnt (float4 stores)
//   - stage W1 -> LDS in MFMA B-fragment lane order directly from global
//   - PQ[e][0:64]   = messages[e] @ W1[0:64, :]          (P, consumed via kj)
//     PQ[e][64:128] = messages[e] @ W1[64:128, :] + b1   (Q, consumed via ji)
// Stored fp16, [E x 128]. One wave = 16 edge rows, 16 MFMAs, one tile/wave.
// ---------------------------------------------------------------------------
__global__ __launch_bounds__(256, 2)
void edge_proj_kernel(const float* __restrict__ messages,
                      const float* __restrict__ W1, const float* __restrict__ b1,
                      _Float16* __restrict__ PQ, int E,
                      float4* __restrict__ zs, int nz4)
{
    __shared__ __align__(16) _Float16 lw1x[16 * 512];     // 16 B-fragments, lane-order
    __shared__ __align__(16) _Float16 lrep[4][16 * 132];  // per-wave C->row repack

    const int tid = threadIdx.x;

    // zero accumulators (grid-strided; 2500 blocks cover 25000 float4)
    {
        float4 z = {0.f, 0.f, 0.f, 0.f};
        for (int i = blockIdx.x * 256 + tid; i < nz4; i += gridDim.x * 256) zs[i] = z;
    }

    // stage W1: row-major [128][64]; rows 0..63 -> P cols, rows 64..127 -> Q cols
    for (int i = tid; i < 128 * 64; i += 256) {
        int r = i >> 6, c = i & 63;
        int k  = (r < 64) ? r : (r - 64);
        int np = (r < 64) ? c : (64 + c);
        int f  = (np >> 4) * 2 + (k >> 5);
        int ln = ((k >> 3) & 3) * 16 + (np & 15);
        lw1x[f * 512 + ln * 8 + (k & 7)] = (_Float16)W1[i];
    }
    __syncthreads();

    const int wave = tid >> 6;
    const int lane = tid & 63;
    const int s = lane & 15;
    const int q = lane >> 4;
    const int e0 = (blockIdx.x * 4 + wave) * 16;
    if (e0 >= E) return;

    float b1v[4];
#pragma unroll
    for (int nt = 0; nt < 4; ++nt) b1v[nt] = b1[nt * 16 + s];

    int er = e0 + s; if (er >= E) er = E - 1;
    const float* mp = messages + (size_t)er * MSGW + q * 8;
    half8 af0 = cvt8(mp);
    half8 af1 = cvt8(mp + 32);

    floatx4 acc[8];
#pragma unroll
    for (int nt = 0; nt < 4; ++nt) { floatx4 z = {0.f, 0.f, 0.f, 0.f}; acc[nt] = z; }
#pragma unroll
    for (int nt = 4; nt < 8; ++nt) {
        float bv = b1v[nt - 4];
        floatx4 iv = {bv, bv, bv, bv};
        acc[nt] = iv;
    }
#pragma unroll
    for (int nt = 0; nt < 8; ++nt) {
        half8 bf0 = *(const half8*)&lw1x[(nt * 2 + 0) * 512 + lane * 8];
        acc[nt] = __builtin_amdgcn_mfma_f32_16x16x32_f16(af0, bf0, acc[nt], 0, 0, 0);
        half8 bf1 = *(const half8*)&lw1x[(nt * 2 + 1) * 512 + lane * 8];
        acc[nt] = __builtin_amdgcn_mfma_f32_16x16x32_f16(af1, bf1, acc[nt], 0, 0, 0);
    }

    // C-layout -> row-major fp16 via wave-private LDS, then coalesced 16B stores.
    _Float16* rep = lrep[wave];
#pragma unroll
    for (int nt = 0; nt < 8; ++nt)
#pragma unroll
        for (int rr = 0; rr < 4; ++rr)
            rep[(q * 4 + rr) * 132 + nt * 16 + s] = (_Float16)acc[nt][rr];
    __asm__ volatile("s_waitcnt lgkmcnt(0)" ::: "memory");

#pragma unroll
    for (int cc = 0; cc < 4; ++cc) {
        int c = cc * 64 + lane;
        int rrow = c >> 4, c16 = c & 15;
        half8 v = *(const half8*)&rep[rrow * 132 + c16 * 8];
        int eg = e0 + rrow;
        if (eg < E)
            *(half8*)&PQ[(size_t)eg * 128 + c16 * 8] = v;
    }
}

// ---------------------------------------------------------------------------
// One 16-triplet tile step: prefetch next tile's operands, compute this
// tile's pooled contribution, rotate state. ALL state passed by reference
// as named scalars -> SSA after inlining, guaranteed register-resident.
// (R8 lesson / rule #20: half8 state ARRAYS indexed per unrolled loop went
//  to LDS scratch: LDS_Block_Size 0->4096, conflicts 160K, 62->86us. Never
//  hold pipeline state in arrays.)
// ---------------------------------------------------------------------------
__device__ __forceinline__ void tile_step(
    const _Float16* __restrict__ PQ, const float* __restrict__ r2,
    const int* __restrict__ idx_kj,
    const half8 (&w2f)[2][4], const float (&b2v)[4], const float (&w3v)[4],
    float b3v, int q, int s, int aa, int bperm_addr, int T, int stride,
    int& t, int& kj, int& kjn, int& t1c,
    half8& pa, half8& pb, half8& qa, half8& qb,
    float2& rkv, float& rjv,
    float& cval_out, int& jn_out, float& rj_out)
{
    // prefetch: idx two tiles ahead; PQ/rk/rj one tile ahead
    int t2 = t + 2 * stride; int t2c = (t2 < T) ? t2 : 0;
    const int kj2 = idx_kj[t2c];
    const _Float16* pkn = PQ + (size_t)kjn * 128 + q * 8;
    const _Float16* pjn = PQ + (size_t)(t1c >> 3) * 128 + 64 + q * 8;
    half8 npa = *(const half8*)pkn;
    half8 npb = *(const half8*)(pkn + 32);
    half8 nqa = *(const half8*)pjn;
    half8 nqb = *(const half8*)(pjn + 32);
    float2 nrk = *(const float2*)(r2 + (size_t)kjn * 2);
    float nrj = r2[(size_t)(t1c >> 3) * 2 + aa];

    jn_out = kj >> 3;                    // idx_j structural
    rj_out = rjv;

    // layer 1 = fp16 add of prefetched PQ fragments + softplus (A-frag layout)
    half8 a20 = sp8(pa + qa);
    half8 a21 = sp8(pb + qb);

    // layer 2: [16 x 64] @ [64 x 64], B from registers
    floatx4 acc2[4];                     // statically indexed: register-resident
#pragma unroll
    for (int nt = 0; nt < 4; ++nt) {
        float bv = b2v[nt];
        floatx4 iv = {bv, bv, bv, bv};
        acc2[nt] = iv;
    }
#pragma unroll
    for (int nt = 0; nt < 4; ++nt) {
        acc2[nt] = __builtin_amdgcn_mfma_f32_16x16x32_f16(a20, w2f[0][nt], acc2[nt], 0, 0, 0);
        acc2[nt] = __builtin_amdgcn_mfma_f32_16x16x32_f16(a21, w2f[1][nt], acc2[nt], 0, 0, 0);
    }

    // layer 3: m = softplus(h2) . W3 ; reduce over 64 cols = 4 regs x 16 lanes
    float part[4];
#pragma unroll
    for (int rr = 0; rr < 4; ++rr) {
        float p = 0.0f;
#pragma unroll
        for (int nt = 0; nt < 4; ++nt)
            p += softplus_f(acc2[nt][rr]) * w3v[nt];
        part[rr] = red16(p);             // all 16 row-lanes: msum[q*4+rr]
    }

    // distribute m to row-owner lanes: local reg-select then one bpermute
    const int rsel = s & 3;
    float mm = part[0];
    mm = (rsel == 1) ? part[1] : mm;
    mm = (rsel == 2) ? part[2] : mm;
    mm = (rsel == 3) ? part[3] : mm;     // lane (s,q) holds msum[q*4 + (s&3)]
    mm = __int_as_float(__builtin_amdgcn_ds_bpermute(bperm_addr, __float_as_int(mm)));
    mm += b3v;                           // lane (s,q) holds m for row s

    // per-edge pooled vector v[b] = sum_k m_k * rk_k[b]; quads carry b = q&1
    float c = mm * ((q & 1) ? rkv.y : rkv.x);
    cval_out = red8(c);                  // lanes 0..7: edge A, 8..15: edge B

    // rotate pipeline state
    t += stride;
    kj = kjn; kjn = kj2; t1c = t2c;
    pa = npa; pb = npb; qa = nqa; qb = nqb;
    rkv = nrk; rjv = nrj;
}

// ---------------------------------------------------------------------------
// Kernel 2: main triplet kernel. TWO independent 16-triplet tiles per wave
// per iteration (ILP x2): tile B's instructions fill tile A's dependency
// bubbles (serial softplus chain, 4-deep DPP red16). All pipeline state in
// named scalars (see tile_step comment). Zero LDS, no barriers, NO epilogue
// sync (R4/R5: fused finalize cost ~245us idle tail; keep it separate).
// W2 fragments gathered once per lane directly from W2 (16 KB, L2-hot).
// Structural facts: idx_ji[t]=t>>3, idx_j[t]=idx_kj[t]>>3.
// launch_bounds (256,3): VGPR cap ~168. R4's (256,6) squeezed to 40 VGPR and
// spilled (WRITE_SIZE 10->117MB, 6.5x slower). DO NOT raise the wave hint.
// ---------------------------------------------------------------------------
__global__ __launch_bounds__(256, 3)
void triplet_mlp2_kernel(const _Float16* __restrict__ PQ,
                         const float* __restrict__ r2,
                         const float* __restrict__ W2,
                         const float* __restrict__ b2,
                         const float* __restrict__ W3, const float* __restrict__ b3,
                         const int* __restrict__ idx_kj,
                         float* __restrict__ sacc, float* __restrict__ cnt,
                         int nChunks)
{
    const int tid = threadIdx.x;
    const int wave = tid >> 6;
    const int lane = tid & 63;
    const int s = lane & 15;
    const int q = lane >> 4;

    // hoist weights: W2 fragments (32 VGPR) gathered with permuted addressing.
    // w2f[ks][nt][j] = W2[k = ks*32 + q*8 + j][n = nt*16 + s]
    half8 w2f[2][4];
#pragma unroll
    for (int ks = 0; ks < 2; ++ks)
#pragma unroll
        for (int nt = 0; nt < 4; ++nt) {
            half8 h;
#pragma unroll
            for (int j = 0; j < 8; ++j)
                h[j] = (_Float16)W2[(ks * 32 + q * 8 + j) * 64 + nt * 16 + s];
            w2f[ks][nt] = h;
        }
    float b2v[4], w3v[4];
#pragma unroll
    for (int nt = 0; nt < 4; ++nt) {
        b2v[nt] = b2[nt * 16 + s];
        w3v[nt] = W3[nt * 16 + s];
    }
    const float b3v = b3[0];
    const int aa = q >> 1;                       // dyad row component this lane handles
    const int bb = q & 1;                        // dyad col component
    const int bperm_addr = (((s >> 2) << 4) + s) << 2;

    const int T = nChunks * 128;                 // 128 triplets per chunk (2 tiles/wave)
    const int stride = gridDim.x * 128;

    // ---- pipeline prologue: tile A and tile B, all named scalars ----
    int tA = blockIdx.x * 128 + wave * 32 + s;          // < T (grid <= nChunks)
    int tB = tA + 16;
    int kjA = idx_kj[tA];
    int kjB = idx_kj[tB];
    int tA1 = tA + stride; int tA1c = (tA1 < T) ? tA1 : 0;
    int tB1 = tB + stride; int tB1c = (tB1 < T) ? tB1 : 0;
    int kjnA = idx_kj[tA1c];
    int kjnB = idx_kj[tB1c];

    const _Float16* pkA = PQ + (size_t)kjA * 128 + q * 8;
    const _Float16* pjA = PQ + (size_t)(tA >> 3) * 128 + 64 + q * 8;
    half8 paA = *(const half8*)pkA;
    half8 pbA = *(const half8*)(pkA + 32);
    half8 qaA = *(const half8*)pjA;
    half8 qbA = *(const half8*)(pjA + 32);
    float2 rkA = *(const float2*)(r2 + (size_t)kjA * 2);
    float rjA = r2[(size_t)(tA >> 3) * 2 + aa];

    const _Float16* pkB = PQ + (size_t)kjB * 128 + q * 8;
    const _Float16* pjB = PQ + (size_t)(tB >> 3) * 128 + 64 + q * 8;
    half8 paB = *(const half8*)pkB;
    half8 pbB = *(const half8*)(pkB + 32);
    half8 qaB = *(const half8*)pjB;
    half8 qbB = *(const half8*)(pjB + 32);
    float2 rkB = *(const float2*)(r2 + (size_t)kjB * 2);
    float rjB = r2[(size_t)(tB >> 3) * 2 + aa];

    for (int chunk = blockIdx.x; chunk < nChunks; chunk += gridDim.x) {
        float cA, cB, rjA_, rjB_;
        int jnA, jnB;

        tile_step(PQ, r2, idx_kj, w2f, b2v, w3v, b3v, q, s, aa, bperm_addr, T, stride,
                  tA, kjA, kjnA, tA1c, paA, pbA, qaA, qbA, rkA, rjA, cA, jnA, rjA_);
        tile_step(PQ, r2, idx_kj, w2f, b2v, w3v, b3v, q, s, aa, bperm_addr, T, stride,
                  tB, kjB, kjnB, tB1c, paB, pbB, qaB, qbB, rkB, rjB, cB, jnB, rjB_);

        // atomics for both tiles (exec-masked, end of body)
        if ((s & 7) == 0) {
            atomicAdd(&sacc[(size_t)jnA * 4 + aa * 2 + bb], rjA_ * cA);
            atomicAdd(&sacc[(size_t)jnB * 4 + aa * 2 + bb], rjB_ * cB);
            if (q == 0) {
                atomicAdd(&cnt[jnA], 8.0f);       // 8 triplets pooled per edge
                atomicAdd(&cnt[jnB], 8.0f);
            }
        }
    }
}

// ---------------------------------------------------------------------------
// Fallback: verified single-pass kernel (used if ws/shape can't take fast path)
// ---------------------------------------------------------------------------
__global__ __launch_bounds__(256, 3)
void triplet_mlp_fb_kernel(const float* __restrict__ messages,
                           const float* __restrict__ r2,
                           const float* __restrict__ W1, const float* __restrict__ b1,
                           const float* __restrict__ W2, const float* __restrict__ b2,
                           const float* __restrict__ W3, const float* __restrict__ b3,
                           const int* __restrict__ idx_kj,
                           float* __restrict__ sacc, float* __restrict__ cnt,
                           int nChunks)
{
    __shared__ _Float16 lw1x[16 * 512];
    __shared__ _Float16 lw2x[8 * 512];
    __shared__ float lb1[64], lb2[64], lw3[64];
    __shared__ _Float16 lh[4][16 * 72];

    const int tid = threadIdx.x;
    for (int i = tid; i < 128 * 64; i += 256) {
        int k = i >> 6, n = i & 63;
        int ks = k >> 5, q = (k >> 3) & 3, j = k & 7;
        int nt = n >> 4, s = n & 15;
        lw1x[(nt * 4 + ks) * 512 + (q * 16 + s) * 8 + j] = (_Float16)W1[i];
    }
    for (int i = tid; i < 64 * 64; i += 256) {
        int k = i >> 6, n = i & 63;
        int ks = k >> 5, q = (k >> 3) & 3, j = k & 7;
        int nt = n >> 4, s = n & 15;
        lw2x[(nt * 2 + ks) * 512 + (q * 16 + s) * 8 + j] = (_Float16)W2[i];
    }
    if (tid < 64) { lb1[tid] = b1[tid]; lb2[tid] = b2[tid]; lw3[tid] = W3[tid]; }
    __syncthreads();

    const int wave = tid >> 6;
    const int lane = tid & 63;
    const int s = lane & 15;
    const int q = lane >> 4;
    const float b3v = b3[0];
    const int T = nChunks * 64;
    const int stride = gridDim.x * 64;

    _Float16* myh = lh[wave];

    int t = blockIdx.x * 64 + wave * 16 + s;
    int kj = (t < T) ? idx_kj[t] : 0;

    for (int chunk = blockIdx.x; chunk < nChunks; chunk += gridDim.x) {
        const int t_next = t + stride;
        const int kj_next = idx_kj[(t_next < T) ? t_next : 0];

        const int ji = t >> 3;
        const int jn = kj >> 3;

        const float* mk = messages + (size_t)kj * MSGW + q * 8;
        const float* mj = messages + (size_t)ji * MSGW + q * 8;
        half8 afr[4];
        afr[0] = cvt8(mk);
        afr[1] = cvt8(mk + 32);
        afr[2] = cvt8(mj);
        afr[3] = cvt8(mj + 32);

        const float rk0 = r2[(size_t)kj * 2];
        const float rk1 = r2[(size_t)kj * 2 + 1];

        floatx4 acc[4];
#pragma unroll
        for (int nt = 0; nt < 4; ++nt) {
            float bv = lb1[nt * 16 + s];
            floatx4 iv = {bv, bv, bv, bv};
            acc[nt] = iv;
        }
#pragma unroll
        for (int ks = 0; ks < 4; ++ks)
#pragma unroll
            for (int nt = 0; nt < 4; ++nt) {
                half8 bf = *(const half8*)&lw1x[(nt * 4 + ks) * 512 + lane * 8];
                acc[nt] = __builtin_amdgcn_mfma_f32_16x16x32_f16(afr[ks], bf, acc[nt], 0, 0, 0);
            }

#pragma unroll
        for (int nt = 0; nt < 4; ++nt)
#pragma unroll
            for (int rr = 0; rr < 4; ++rr)
                myh[(q * 4 + rr) * 72 + nt * 16 + s] = (_Float16)softplus_f(acc[nt][rr]);
        __asm__ volatile("s_waitcnt lgkmcnt(0)" ::: "memory");

        half8 a2[2];
        a2[0] = *(const half8*)&myh[s * 72 + q * 8];
        a2[1] = *(const half8*)&myh[s * 72 + 32 + q * 8];
        __asm__ volatile("" ::: "memory");

        floatx4 acc2[4];
#pragma unroll
        for (int nt = 0; nt < 4; ++nt) {
            float bv = lb2[nt * 16 + s];
            floatx4 iv = {bv, bv, bv, bv};
            acc2[nt] = iv;
        }
#pragma unroll
        for (int ks = 0; ks < 2; ++ks)
#pragma unroll
            for (int nt = 0; nt < 4; ++nt) {
                half8 bf = *(const half8*)&lw2x[(nt * 2 + ks) * 512 + lane * 8];
                acc2[nt] = __builtin_amdgcn_mfma_f32_16x16x32_f16(a2[ks], bf, acc2[nt], 0, 0, 0);
            }

        float part[4];
#pragma unroll
        for (int rr = 0; rr < 4; ++rr) {
            float p = 0.0f;
#pragma unroll
            for (int nt = 0; nt < 4; ++nt)
                p += softplus_f(acc2[nt][rr]) * lw3[nt * 16 + s];
            part[rr] = p;
        }
#pragma unroll
        for (int mask = 1; mask < 16; mask <<= 1)
#pragma unroll
            for (int rr = 0; rr < 4; ++rr)
                part[rr] += __shfl_xor(part[rr], mask, 16);

        const int srcl = (s >> 2) << 4;
        float mr[4];
#pragma unroll
        for (int rr = 0; rr < 4; ++rr)
            mr[rr] = __shfl(part[rr], srcl, 64);
        const int rsel = s & 3;
        float m_mine = mr[0];
        m_mine = (rsel == 1) ? mr[1] : m_mine;
        m_mine = (rsel == 2) ? mr[2] : m_mine;
        m_mine = (rsel == 3) ? mr[3] : m_mine;
        m_mine += b3v;

        float c = m_mine * ((q & 1) ? rk1 : rk0);
        c += __shfl_xor(c, 1, 16);
        c += __shfl_xor(c, 2, 16);
        c += __shfl_xor(c, 4, 16);

        if ((s & 7) == 0) {
            const int aa = q >> 1, bb = q & 1;
            const float rj = r2[(size_t)ji * 2 + aa];
            atomicAdd(&sacc[(size_t)jn * 4 + aa * 2 + bb], rj * c);
            if (q == 0) atomicAdd(&cnt[jn], 8.0f);
        }

        t = t_next;
        kj = kj_next;
    }
}

__global__ void finalize_kernel(const float* __restrict__ sacc, const float* __restrict__ cnt,
                                float* __restrict__ out, int n4) {
    int i = blockIdx.x * 256 + threadIdx.x;
    if (i < n4) {
        float c = cnt[i >> 2];
        out[i] = sacc[i] / fmaxf(c, 1.0f);
    }
}

extern "C" void kernel_launch(void* const* d_in, const int* in_sizes, int n_in,
                              void* d_out, int out_size, void* d_ws, size_t ws_size,
                              hipStream_t stream) {
    const float* messages = (const float*)d_in[0];
    const float* r2       = (const float*)d_in[1];
    const float* W1       = (const float*)d_in[2];
    const float* b1       = (const float*)d_in[3];
    const float* W2       = (const float*)d_in[4];
    const float* b2       = (const float*)d_in[5];
    const float* W3       = (const float*)d_in[6];
    const float* b3       = (const float*)d_in[7];
    const int* idx_kj     = (const int*)d_in[8];

    const int T = in_sizes[8];          // 1,280,000 triplets
    const int E = T / DEG;              // 160,000 edges
    const int N = out_size / 4;         // 20,000 nodes
    float* sacc = (float*)d_ws;         // [N*4] pooled sums
    float* cntp = sacc + (size_t)N * 4; // [N] counts

    const int n4 = N * 4;

    // zeroed span: N*5 floats (sacc+cnt), in float4 units (N*5 divisible by 4)
    const int nz4 = (N * 5) / 4;
    const size_t zBytes = (size_t)nz4 * 16;
    const size_t pqOff  = (zBytes + 255) & ~(size_t)255;
    const size_t needWs = pqOff + (size_t)E * 128 * sizeof(_Float16);

    if (ws_size >= needWs && (T % 128) == 0) {
        _Float16* PQ = (_Float16*)((char*)d_ws + pqOff);

        const int tiles = (E + 15) / 16;            // 16-edge wave tiles
        const int epgrid = (tiles + 3) / 4;         // one tile per wave, 4 waves/block
        edge_proj_kernel<<<epgrid, 256, 0, stream>>>(messages, W1, b1, PQ, E,
                                                     (float4*)d_ws, nz4);

        const int nChunks = T / 128;                // 128 triplets/chunk (2 tiles/wave)
        int grid = nChunks < 2048 ? nChunks : 2048;
        triplet_mlp2_kernel<<<grid, 256, 0, stream>>>(PQ, r2, W2, b2, W3, b3,
                                                      idx_kj, sacc, cntp, nChunks);
    } else {
        const int nChunks = T / 64;
        int grid = nChunks < 2048 ? nChunks : 2048;
        (void)hipMemsetAsync(d_ws, 0, (size_t)N * 5 * sizeof(float), stream);
        triplet_mlp_fb_kernel<<<grid, 256, 0, stream>>>(messages, r2, W1, b1, W2, b2, W3, b3,
                                                        idx_kj, sacc, cntp, nChunks);
    }

    finalize_kernel<<<(n4 + 255) / 256, 256, 0, stream>>>(sacc, cntp, (float*)d_out, n4);
}

// Round 10
// 174.695 us; speedup vs baseline: 1.1348x; 1.1245x over previous
//
#include <hip/hip_runtime.h>

// MFMA fragment types (gfx950): 16x16x32 f16 -> A/B = 8 x _Float16, C/D = 4 x float
typedef _Float16 half8 __attribute__((ext_vector_type(8)));
typedef __fp16 fp16x2 __attribute__((ext_vector_type(2)));   // cvt_pkrtz return type
typedef float floatx4 __attribute__((ext_vector_type(4)));

#define MSGW 64      // message width
#define DEG 8        // fixed in-degree; triplets per edge

// softplus(x) = ln(1 + e^x) = ln2 * log2(1 + exp2(log2e * x))
// 5 VALU ops; valid for x < ~88 (exp2 overflow), net's pre-activations |x| <~ 50.
__device__ __forceinline__ float softplus_f(float x) {
    float t = __builtin_amdgcn_exp2f(1.44269504089f * x);    // e^x
    return 0.69314718056f * __builtin_amdgcn_logf(1.0f + t); // ln(1+e^x)
}

__device__ __forceinline__ half8 cvt8(const float* p) {
    float4 x = *(const float4*)p;
    float4 y = *(const float4*)(p + 4);
    fp16x2 p0 = __builtin_amdgcn_cvt_pkrtz(x.x, x.y);
    fp16x2 p1 = __builtin_amdgcn_cvt_pkrtz(x.z, x.w);
    fp16x2 p2 = __builtin_amdgcn_cvt_pkrtz(y.x, y.y);
    fp16x2 p3 = __builtin_amdgcn_cvt_pkrtz(y.z, y.w);
    half8 h;
    h[0] = (_Float16)p0[0]; h[1] = (_Float16)p0[1];
    h[2] = (_Float16)p1[0]; h[3] = (_Float16)p1[1];
    h[4] = (_Float16)p2[0]; h[5] = (_Float16)p2[1];
    h[6] = (_Float16)p3[0]; h[7] = (_Float16)p3[1];
    return h;
}

// softplus over a half8 (fp16 in, fp16 out via cvt_pkrtz pairs)
__device__ __forceinline__ half8 sp8(half8 z) {
    half8 h;
#pragma unroll
    for (int j = 0; j < 8; j += 2) {
        fp16x2 pk = __builtin_amdgcn_cvt_pkrtz(softplus_f((float)z[j]),
                                               softplus_f((float)z[j + 1]));
        h[j] = (_Float16)pk[0]; h[j + 1] = (_Float16)pk[1];
    }
    return h;
}

// DPP-based cross-lane adds (register-only, no DS pipe).
template<int CTRL>
__device__ __forceinline__ float dpp_addf(float x) {
    int y = __builtin_amdgcn_update_dpp(0, __float_as_int(x), CTRL, 0xF, 0xF, true);
    return x + __int_as_float(y);
}
// full sum over the 16 lanes of a DPP row
__device__ __forceinline__ float red16(float x) {
    x = dpp_addf<0xB1>(x);   // pair sums
    x = dpp_addf<0x4E>(x);   // quad sums
    x = dpp_addf<0x141>(x);  // 8-lane sums
    x = dpp_addf<0x140>(x);  // 16-lane sum (all lanes)
    return x;
}
// sum over each 8-lane half of a DPP row
__device__ __forceinline__ float red8(float x) {
    x = dpp_addf<0xB1>(x);
    x = dpp_addf<0x4E>(x);
    x = dpp_addf<0x141>(x);
    return x;
}

// ---------------------------------------------------------------------------
// Kernel 1 (fused prep + projection):
//   - grid-stride zero of sacc/cnt (float4 stores)
//   - stage W1 -> LDS in MFMA B-fragment lane order directly from global
//   - PQ[e][0:64]   = messages[e] @ W1[0:64, :]          (P, consumed via kj)
//     PQ[e][64:128] = messages[e] @ W1[64:128, :] + b1   (Q, consumed via ji)
// Stored fp16, [E x 128]. One wave = 16 edge rows, 16 MFMAs, one tile/wave.
// ---------------------------------------------------------------------------
__global__ __launch_bounds__(256, 2)
void edge_proj_kernel(const float* __restrict__ messages,
                      const float* __restrict__ W1, const float* __restrict__ b1,
                      _Float16* __restrict__ PQ, int E,
                      float4* __restrict__ zs, int nz4)
{
    __shared__ __align__(16) _Float16 lw1x[16 * 512];     // 16 B-fragments, lane-order
    __shared__ __align__(16) _Float16 lrep[4][16 * 132];  // per-wave C->row repack

    const int tid = threadIdx.x;

    // zero accumulators (grid-strided; 2500 blocks cover 25000 float4)
    {
        float4 z = {0.f, 0.f, 0.f, 0.f};
        for (int i = blockIdx.x * 256 + tid; i < nz4; i += gridDim.x * 256) zs[i] = z;
    }

    // stage W1: row-major [128][64]; rows 0..63 -> P cols, rows 64..127 -> Q cols
    for (int i = tid; i < 128 * 64; i += 256) {
        int r = i >> 6, c = i & 63;
        int k  = (r < 64) ? r : (r - 64);
        int np = (r < 64) ? c : (64 + c);
        int f  = (np >> 4) * 2 + (k >> 5);
        int ln = ((k >> 3) & 3) * 16 + (np & 15);
        lw1x[f * 512 + ln * 8 + (k & 7)] = (_Float16)W1[i];
    }
    __syncthreads();

    const int wave = tid >> 6;
    const int lane = tid & 63;
    const int s = lane & 15;
    const int q = lane >> 4;
    const int e0 = (blockIdx.x * 4 + wave) * 16;
    if (e0 >= E) return;

    float b1v[4];
#pragma unroll
    for (int nt = 0; nt < 4; ++nt) b1v[nt] = b1[nt * 16 + s];

    int er = e0 + s; if (er >= E) er = E - 1;
    const float* mp = messages + (size_t)er * MSGW + q * 8;
    half8 af0 = cvt8(mp);
    half8 af1 = cvt8(mp + 32);

    floatx4 acc[8];
#pragma unroll
    for (int nt = 0; nt < 4; ++nt) { floatx4 z = {0.f, 0.f, 0.f, 0.f}; acc[nt] = z; }
#pragma unroll
    for (int nt = 4; nt < 8; ++nt) {
        float bv = b1v[nt - 4];
        floatx4 iv = {bv, bv, bv, bv};
        acc[nt] = iv;
    }
#pragma unroll
    for (int nt = 0; nt < 8; ++nt) {
        half8 bf0 = *(const half8*)&lw1x[(nt * 2 + 0) * 512 + lane * 8];
        acc[nt] = __builtin_amdgcn_mfma_f32_16x16x32_f16(af0, bf0, acc[nt], 0, 0, 0);
        half8 bf1 = *(const half8*)&lw1x[(nt * 2 + 1) * 512 + lane * 8];
        acc[nt] = __builtin_amdgcn_mfma_f32_16x16x32_f16(af1, bf1, acc[nt], 0, 0, 0);
    }

    // C-layout -> row-major fp16 via wave-private LDS, then coalesced 16B stores.
    _Float16* rep = lrep[wave];
#pragma unroll
    for (int nt = 0; nt < 8; ++nt)
#pragma unroll
        for (int rr = 0; rr < 4; ++rr)
            rep[(q * 4 + rr) * 132 + nt * 16 + s] = (_Float16)acc[nt][rr];
    __asm__ volatile("s_waitcnt lgkmcnt(0)" ::: "memory");

#pragma unroll
    for (int cc = 0; cc < 4; ++cc) {
        int c = cc * 64 + lane;
        int rrow = c >> 4, c16 = c & 15;
        half8 v = *(const half8*)&rep[rrow * 132 + c16 * 8];
        int eg = e0 + rrow;
        if (eg < E)
            *(half8*)&PQ[(size_t)eg * 128 + c16 * 8] = v;
    }
}

// ---------------------------------------------------------------------------
// 2-tile ILP via token-pasted macros: ZERO address-taking.
// R8/R9 lesson: passing state (even named scalars) BY REFERENCE into a
// helper creates allocas -> AMDGPUPromoteAlloca moves them to LDS
// (LDS_Block_Size 4096 = 256 thr x one half8, VGPR squeezed to 64,
// VALUBusy 52%, 62->84us). Macros generate R7's proven straight-line body
// twice with _A/_B suffixed names in ONE basic block: SSA guaranteed,
// scheduler interleaves tile B into tile A's dependency bubbles.
// w2f/b2v/w3v/acc2/part: constant-indexed local arrays (R7-proven VGPR-resident).
// ---------------------------------------------------------------------------
#define TILE_STATE(S) \
    int t_##S, kj_##S, kjn_##S, t1c_##S; \
    half8 pa_##S, pb_##S, qa_##S, qb_##S; \
    float2 rk_##S; float rj_##S;

#define TILE_INIT(S, T0) \
    t_##S = (T0); \
    kj_##S = idx_kj[t_##S]; \
    { int t1_ = t_##S + stride; t1c_##S = (t1_ < T) ? t1_ : 0; } \
    kjn_##S = idx_kj[t1c_##S]; \
    { const _Float16* pk_ = PQ + (size_t)kj_##S * 128 + q * 8; \
      const _Float16* pj_ = PQ + (size_t)(t_##S >> 3) * 128 + 64 + q * 8; \
      pa_##S = *(const half8*)pk_; pb_##S = *(const half8*)(pk_ + 32); \
      qa_##S = *(const half8*)pj_; qb_##S = *(const half8*)(pj_ + 32); } \
    rk_##S = *(const float2*)(r2 + (size_t)kj_##S * 2); \
    rj_##S = r2[(size_t)(t_##S >> 3) * 2 + aa];

// prefetch next tile's operands, compute this tile's pooled contribution
// (cval_S, jn_S, rjv_S), rotate state. Straight-line, no branches.
#define TILE_STEP(S) \
    int t2_##S = t_##S + 2 * stride; int t2c_##S = (t2_##S < T) ? t2_##S : 0; \
    const int kj2_##S = idx_kj[t2c_##S]; \
    const _Float16* pkn_##S = PQ + (size_t)kjn_##S * 128 + q * 8; \
    const _Float16* pjn_##S = PQ + (size_t)(t1c_##S >> 3) * 128 + 64 + q * 8; \
    half8 npa_##S = *(const half8*)pkn_##S; \
    half8 npb_##S = *(const half8*)(pkn_##S + 32); \
    half8 nqa_##S = *(const half8*)pjn_##S; \
    half8 nqb_##S = *(const half8*)(pjn_##S + 32); \
    float2 nrk_##S = *(const float2*)(r2 + (size_t)kjn_##S * 2); \
    float nrj_##S = r2[(size_t)(t1c_##S >> 3) * 2 + aa]; \
    const int jn_##S = kj_##S >> 3; \
    const float rjv_##S = rj_##S; \
    half8 a20_##S = sp8(pa_##S + qa_##S); \
    half8 a21_##S = sp8(pb_##S + qb_##S); \
    floatx4 acc2_##S[4]; \
    _Pragma("unroll") \
    for (int nt = 0; nt < 4; ++nt) { \
        float bv = b2v[nt]; floatx4 iv = {bv, bv, bv, bv}; acc2_##S[nt] = iv; } \
    _Pragma("unroll") \
    for (int nt = 0; nt < 4; ++nt) { \
        acc2_##S[nt] = __builtin_amdgcn_mfma_f32_16x16x32_f16(a20_##S, w2f[0][nt], acc2_##S[nt], 0, 0, 0); \
        acc2_##S[nt] = __builtin_amdgcn_mfma_f32_16x16x32_f16(a21_##S, w2f[1][nt], acc2_##S[nt], 0, 0, 0); } \
    float part_##S[4]; \
    _Pragma("unroll") \
    for (int rr = 0; rr < 4; ++rr) { \
        float p_ = 0.0f; \
        _Pragma("unroll") \
        for (int nt = 0; nt < 4; ++nt) p_ += softplus_f(acc2_##S[nt][rr]) * w3v[nt]; \
        part_##S[rr] = red16(p_); } \
    float mm_##S = part_##S[0]; \
    mm_##S = (rsel == 1) ? part_##S[1] : mm_##S; \
    mm_##S = (rsel == 2) ? part_##S[2] : mm_##S; \
    mm_##S = (rsel == 3) ? part_##S[3] : mm_##S; \
    mm_##S = __int_as_float(__builtin_amdgcn_ds_bpermute(bperm_addr, __float_as_int(mm_##S))); \
    mm_##S += b3v; \
    float cval_##S = red8(mm_##S * ((q & 1) ? rk_##S.y : rk_##S.x)); \
    t_##S += stride; \
    kj_##S = kjn_##S; kjn_##S = kj2_##S; t1c_##S = t2c_##S; \
    pa_##S = npa_##S; pb_##S = npb_##S; qa_##S = nqa_##S; qb_##S = nqb_##S; \
    rk_##S = nrk_##S; rj_##S = nrj_##S;

// ---------------------------------------------------------------------------
// Kernel 2: main triplet kernel, 2 tiles/wave/iter (ILP x2), zero LDS, no
// barriers, NO epilogue sync (R4/R5: fused finalize = ~245us idle tail).
// W2 fragments gathered once per lane directly from W2 (16 KB, L2-hot).
// Structural facts: idx_ji[t]=t>>3, idx_j[t]=idx_kj[t]>>3.
// launch_bounds (256,3): VGPR cap ~170. R4's (256,6) squeezed to 40 and
// spilled to scratch (WRITE_SIZE 117MB). DO NOT raise the wave hint.
// ---------------------------------------------------------------------------
__global__ __launch_bounds__(256, 3)
void triplet_mlp2_kernel(const _Float16* __restrict__ PQ,
                         const float* __restrict__ r2,
                         const float* __restrict__ W2,
                         const float* __restrict__ b2,
                         const float* __restrict__ W3, const float* __restrict__ b3,
                         const int* __restrict__ idx_kj,
                         float* __restrict__ sacc, float* __restrict__ cnt,
                         int nChunks)
{
    const int tid = threadIdx.x;
    const int wave = tid >> 6;
    const int lane = tid & 63;
    const int s = lane & 15;
    const int q = lane >> 4;

    // hoist weights: W2 fragments (32 VGPR) gathered with permuted addressing.
    // w2f[ks][nt][j] = W2[k = ks*32 + q*8 + j][n = nt*16 + s]
    half8 w2f[2][4];
#pragma unroll
    for (int ks = 0; ks < 2; ++ks)
#pragma unroll
        for (int nt = 0; nt < 4; ++nt) {
            half8 h;
#pragma unroll
            for (int j = 0; j < 8; ++j)
                h[j] = (_Float16)W2[(ks * 32 + q * 8 + j) * 64 + nt * 16 + s];
            w2f[ks][nt] = h;
        }
    float b2v[4], w3v[4];
#pragma unroll
    for (int nt = 0; nt < 4; ++nt) {
        b2v[nt] = b2[nt * 16 + s];
        w3v[nt] = W3[nt * 16 + s];
    }
    const float b3v = b3[0];
    const int aa = q >> 1;                       // dyad row component this lane handles
    const int bb = q & 1;                        // dyad col component
    const int rsel = s & 3;
    const int bperm_addr = (((s >> 2) << 4) + s) << 2;

    const int T = nChunks * 128;                 // 128 triplets per chunk (2 tiles/wave)
    const int stride = gridDim.x * 128;

    // ---- pipeline prologue: tile A and tile B, all named scalars ----
    TILE_STATE(A)
    TILE_STATE(B)
    TILE_INIT(A, blockIdx.x * 128 + wave * 32 + s)
    TILE_INIT(B, t_A + 16)

    for (int chunk = blockIdx.x; chunk < nChunks; chunk += gridDim.x) {
        TILE_STEP(A)
        TILE_STEP(B)

        // atomics for both tiles (exec-masked, end of body)
        if ((s & 7) == 0) {
            atomicAdd(&sacc[(size_t)jn_A * 4 + aa * 2 + bb], rjv_A * cval_A);
            atomicAdd(&sacc[(size_t)jn_B * 4 + aa * 2 + bb], rjv_B * cval_B);
            if (q == 0) {
                atomicAdd(&cnt[jn_A], 8.0f);      // 8 triplets pooled per edge
                atomicAdd(&cnt[jn_B], 8.0f);
            }
        }
    }
}

// ---------------------------------------------------------------------------
// Fallback: verified single-pass kernel (used if ws/shape can't take fast path)
// ---------------------------------------------------------------------------
__global__ __launch_bounds__(256, 3)
void triplet_mlp_fb_kernel(const float* __restrict__ messages,
                           const float* __restrict__ r2,
                           const float* __restrict__ W1, const float* __restrict__ b1,
                           const float* __restrict__ W2, const float* __restrict__ b2,
                           const float* __restrict__ W3, const float* __restrict__ b3,
                           const int* __restrict__ idx_kj,
                           float* __restrict__ sacc, float* __restrict__ cnt,
                           int nChunks)
{
    __shared__ _Float16 lw1x[16 * 512];
    __shared__ _Float16 lw2x[8 * 512];
    __shared__ float lb1[64], lb2[64], lw3[64];
    __shared__ _Float16 lh[4][16 * 72];

    const int tid = threadIdx.x;
    for (int i = tid; i < 128 * 64; i += 256) {
        int k = i >> 6, n = i & 63;
        int ks = k >> 5, q = (k >> 3) & 3, j = k & 7;
        int nt = n >> 4, s = n & 15;
        lw1x[(nt * 4 + ks) * 512 + (q * 16 + s) * 8 + j] = (_Float16)W1[i];
    }
    for (int i = tid; i < 64 * 64; i += 256) {
        int k = i >> 6, n = i & 63;
        int ks = k >> 5, q = (k >> 3) & 3, j = k & 7;
        int nt = n >> 4, s = n & 15;
        lw2x[(nt * 2 + ks) * 512 + (q * 16 + s) * 8 + j] = (_Float16)W2[i];
    }
    if (tid < 64) { lb1[tid] = b1[tid]; lb2[tid] = b2[tid]; lw3[tid] = W3[tid]; }
    __syncthreads();

    const int wave = tid >> 6;
    const int lane = tid & 63;
    const int s = lane & 15;
    const int q = lane >> 4;
    const float b3v = b3[0];
    const int T = nChunks * 64;
    const int stride = gridDim.x * 64;

    _Float16* myh = lh[wave];

    int t = blockIdx.x * 64 + wave * 16 + s;
    int kj = (t < T) ? idx_kj[t] : 0;

    for (int chunk = blockIdx.x; chunk < nChunks; chunk += gridDim.x) {
        const int t_next = t + stride;
        const int kj_next = idx_kj[(t_next < T) ? t_next : 0];

        const int ji = t >> 3;
        const int jn = kj >> 3;

        const float* mk = messages + (size_t)kj * MSGW + q * 8;
        const float* mj = messages + (size_t)ji * MSGW + q * 8;
        half8 afr[4];
        afr[0] = cvt8(mk);
        afr[1] = cvt8(mk + 32);
        afr[2] = cvt8(mj);
        afr[3] = cvt8(mj + 32);

        const float rk0 = r2[(size_t)kj * 2];
        const float rk1 = r2[(size_t)kj * 2 + 1];

        floatx4 acc[4];
#pragma unroll
        for (int nt = 0; nt < 4; ++nt) {
            float bv = lb1[nt * 16 + s];
            floatx4 iv = {bv, bv, bv, bv};
            acc[nt] = iv;
        }
#pragma unroll
        for (int ks = 0; ks < 4; ++ks)
#pragma unroll
            for (int nt = 0; nt < 4; ++nt) {
                half8 bf = *(const half8*)&lw1x[(nt * 4 + ks) * 512 + lane * 8];
                acc[nt] = __builtin_amdgcn_mfma_f32_16x16x32_f16(afr[ks], bf, acc[nt], 0, 0, 0);
            }

#pragma unroll
        for (int nt = 0; nt < 4; ++nt)
#pragma unroll
            for (int rr = 0; rr < 4; ++rr)
                myh[(q * 4 + rr) * 72 + nt * 16 + s] = (_Float16)softplus_f(acc[nt][rr]);
        __asm__ volatile("s_waitcnt lgkmcnt(0)" ::: "memory");

        half8 a2[2];
        a2[0] = *(const half8*)&myh[s * 72 + q * 8];
        a2[1] = *(const half8*)&myh[s * 72 + 32 + q * 8];
        __asm__ volatile("" ::: "memory");

        floatx4 acc2[4];
#pragma unroll
        for (int nt = 0; nt < 4; ++nt) {
            float bv = lb2[nt * 16 + s];
            floatx4 iv = {bv, bv, bv, bv};
            acc2[nt] = iv;
        }
#pragma unroll
        for (int ks = 0; ks < 2; ++ks)
#pragma unroll
            for (int nt = 0; nt < 4; ++nt) {
                half8 bf = *(const half8*)&lw2x[(nt * 2 + ks) * 512 + lane * 8];
                acc2[nt] = __builtin_amdgcn_mfma_f32_16x16x32_f16(a2[ks], bf, acc2[nt], 0, 0, 0);
            }

        float part[4];
#pragma unroll
        for (int rr = 0; rr < 4; ++rr) {
            float p = 0.0f;
#pragma unroll
            for (int nt = 0; nt < 4; ++nt)
                p += softplus_f(acc2[nt][rr]) * lw3[nt * 16 + s];
            part[rr] = p;
        }
#pragma unroll
        for (int mask = 1; mask < 16; mask <<= 1)
#pragma unroll
            for (int rr = 0; rr < 4; ++rr)
                part[rr] += __shfl_xor(part[rr], mask, 16);

        const int srcl = (s >> 2) << 4;
        float mr[4];
#pragma unroll
        for (int rr = 0; rr < 4; ++rr)
            mr[rr] = __shfl(part[rr], srcl, 64);
        const int rsel = s & 3;
        float m_mine = mr[0];
        m_mine = (rsel == 1) ? mr[1] : m_mine;
        m_mine = (rsel == 2) ? mr[2] : m_mine;
        m_mine = (rsel == 3) ? mr[3] : m_mine;
        m_mine += b3v;

        float c = m_mine * ((q & 1) ? rk1 : rk0);
        c += __shfl_xor(c, 1, 16);
        c += __shfl_xor(c, 2, 16);
        c += __shfl_xor(c, 4, 16);

        if ((s & 7) == 0) {
            const int aa = q >> 1, bb = q & 1;
            const float rj = r2[(size_t)ji * 2 + aa];
            atomicAdd(&sacc[(size_t)jn * 4 + aa * 2 + bb], rj * c);
            if (q == 0) atomicAdd(&cnt[jn], 8.0f);
        }

        t = t_next;
        kj = kj_next;
    }
}

__global__ void finalize_kernel(const float* __restrict__ sacc, const float* __restrict__ cnt,
                                float* __restrict__ out, int n4) {
    int i = blockIdx.x * 256 + threadIdx.x;
    if (i < n4) {
        float c = cnt[i >> 2];
        out[i] = sacc[i] / fmaxf(c, 1.0f);
    }
}

extern "C" void kernel_launch(void* const* d_in, const int* in_sizes, int n_in,
                              void* d_out, int out_size, void* d_ws, size_t ws_size,
                              hipStream_t stream) {
    const float* messages = (const float*)d_in[0];
    const float* r2       = (const float*)d_in[1];
    const float* W1       = (const float*)d_in[2];
    const float* b1       = (const float*)d_in[3];
    const float* W2       = (const float*)d_in[4];
    const float* b2       = (const float*)d_in[5];
    const float* W3       = (const float*)d_in[6];
    const float* b3       = (const float*)d_in[7];
    const int* idx_kj     = (const int*)d_in[8];

    const int T = in_sizes[8];          // 1,280,000 triplets
    const int E = T / DEG;              // 160,000 edges
    const int N = out_size / 4;         // 20,000 nodes
    float* sacc = (float*)d_ws;         // [N*4] pooled sums
    float* cntp = sacc + (size_t)N * 4; // [N] counts

    const int n4 = N * 4;

    // zeroed span: N*5 floats (sacc+cnt), in float4 units (N*5 divisible by 4)
    const int nz4 = (N * 5) / 4;
    const size_t zBytes = (size_t)nz4 * 16;
    const size_t pqOff  = (zBytes + 255) & ~(size_t)255;
    const size_t needWs = pqOff + (size_t)E * 128 * sizeof(_Float16);

    if (ws_size >= needWs && (T % 128) == 0) {
        _Float16* PQ = (_Float16*)((char*)d_ws + pqOff);

        const int tiles = (E + 15) / 16;            // 16-edge wave tiles
        const int epgrid = (tiles + 3) / 4;         // one tile per wave, 4 waves/block
        edge_proj_kernel<<<epgrid, 256, 0, stream>>>(messages, W1, b1, PQ, E,
                                                     (float4*)d_ws, nz4);

        const int nChunks = T / 128;                // 128 triplets/chunk (2 tiles/wave)
        int grid = nChunks < 2048 ? nChunks : 2048;
        triplet_mlp2_kernel<<<grid, 256, 0, stream>>>(PQ, r2, W2, b2, W3, b3,
                                                      idx_kj, sacc, cntp, nChunks);
    } else {
        const int nChunks = T / 64;
        int grid = nChunks < 2048 ? nChunks : 2048;
        (void)hipMemsetAsync(d_ws, 0, (size_t)N * 5 * sizeof(float), stream);
        triplet_mlp_fb_kernel<<<grid, 256, 0, stream>>>(messages, r2, W1, b1, W2, b2, W3, b3,
                                                        idx_kj, sacc, cntp, nChunks);
    }

    finalize_kernel<<<(n4 + 255) / 256, 256, 0, stream>>>(sacc, cntp, (float*)d_out, n4);
}